// Round 13
// baseline (340.232 us; speedup 1.0000x reference)
//
#include <hip/hip_runtime.h>
#include <hip/hip_bf16.h>

#define N_NODES 50000
#define N_E0    800000
#define N_ET    850000
#define EPSBN   1e-5f
#define LOG2E   1.4426950408889634f

#define LEAKY(z) fmaxf((z), 0.2f * (z))

// ---- workspace layout (32-bit word offsets) ----
#define OFF_C 0                 // layer1 C bf16-packed (64N words); overlaid by DSTB/SRCB during CSR build; layer2 C f32
#define OFF_A (128*N_NODES)     // xl2b (bf16) / xl3
#define OFF_B (192*N_NODES)     // xr2 (f32) / xr3
#define OFF_STATS (256*N_NODES)
#define OFF_S1R (OFF_STATS + 512)            // 64 replicas x 256
#define OFF_S2R (OFF_S1R + 16384)            // 64 replicas x 128
#define OFF_P (OFF_S2R + 8192)
#define N_PARAM_TOT 118312
#define OFF_ROWPTR (OFF_P + N_PARAM_TOT)      // 50001 ints
#define OFF_DEG    (OFF_ROWPTR + 50001)       // 50000 ints
#define OFF_CURSOR (OFF_DEG + 50000)          // 50000 ints
#define OFF_BSUM   (OFF_CURSOR + 50000)       // 256 ints
#define OFF_COL    (OFF_BSUM + 256)           // 850000 + 64 pad ints
#define OFF_FLAGS  (OFF_COL + 850064)         // 2 ints
#define OFF_SCNT   (OFF_FLAGS + 2)            // 8 stripe cursors

// per-stripe bucket segments, overlaid on the C region (C written later)
#define BK_CAP 131072
#define BK_CHUNK 2048

__device__ __forceinline__ float bf2f(unsigned short u) {
    return __uint_as_float(((unsigned int)u) << 16);
}
__device__ __forceinline__ unsigned short f2bf(float f) {
    unsigned int u = __float_as_uint(f);
    u += 0x7FFFu + ((u >> 16) & 1u);    // round-to-nearest-even
    return (unsigned short)(u >> 16);
}

// ---- prep: dtype detect (block 0) + deg/stats/replica/scnt init ----
__global__ void prep_kernel(const unsigned short* xr, const int* ei, int* flags,
                            int* deg, float* stats, float* s1r, float* s2r, int* scnt) {
    int i = blockIdx.x * 256 + threadIdx.x;
    if (i < N_NODES) deg[i] = 0;   // self-loops flow through bucket path
    if (i < 512) stats[i] = 0.f;
    if (i < 16384) s1r[i] = 0.f;
    if (i < 8192)  s2r[i] = 0.f;
    if (i < 8) scnt[i] = 0;
    if (blockIdx.x == 0) {
        __shared__ int c1, c2;
        if (threadIdx.x == 0) { c1 = 0; c2 = 0; }
        __syncthreads();
        int t = threadIdx.x;
        int l1 = 0, l2 = 0;
        for (int k = t; k < 2048; k += 256) {
            float v = bf2f(xr[k]);
            if (!(fabsf(v) <= 100.0f)) l1++;
            if (ei[2 * k + 1] != 0) l2++;
        }
        atomicAdd(&c1, l1);
        atomicAdd(&c2, l2);
        __syncthreads();
        if (t == 0) {
            flags[0] = (c1 > 16) ? 1 : 0;   // 1 => inputs are f32
            flags[1] = (c2 == 0) ? 1 : 0;   // 1 => edge_index is int64
        }
    }
}

struct ParamPtrs { const void* p[23]; };

// stage f32 params; att vectors (t=5,13,21) pre-scaled by log2e so softmax uses exp2
__global__ void convert_kernel(ParamPtrs ps, float* dst, const int* flags) {
    const int sizes[23] = {100000, 256,128,256,128,128,128,128,128,
                           8192,64,8192,64,64,64,64,64,
                           128,2,128,2,2,2};
    int g = blockIdx.x * 256 + threadIdx.x;
    if (g >= N_PARAM_TOT) return;
    int t = 0, off = g;
    while (off >= sizes[t]) { off -= sizes[t]; t++; }
    float v;
    if (flags[0]) v = ((const float*)ps.p[t])[off];
    else          v = bf2f(((const unsigned short*)ps.p[t])[off]);
    if (t == 5 || t == 13 || t == 21) v *= LOG2E;
    dst[g] = v;
}

// ---- pass 1: read edges ONCE, bucket (dst,src) into 8 per-stripe segments ----
__global__ void bucket_kernel(const int* ei, const int* flags, int* scnt,
                              int* dstb, int* srcb) {
    __shared__ int lcnt[8];
    __shared__ int lbase[8];
    int tid = threadIdx.x;
    if (tid < 8) lcnt[tid] = 0;
    __syncthreads();
    int base_e = blockIdx.x * BK_CHUNK;
    int i64 = flags[1];
    int src[8], dst[8], pos[8];
    #pragma unroll
    for (int u = 0; u < 8; u++) {
        int e = base_e + u * 256 + tid;
        if (e < N_ET) {
            int s, d;
            if (e < N_E0) {
                d = i64 ? ei[2 * (N_E0 + e)] : ei[N_E0 + e];
                s = i64 ? ei[2 * e] : ei[e];
            } else { s = d = e - N_E0; }
            src[u] = s; dst[u] = d;
            pos[u] = atomicAdd(&lcnt[d / 6250], 1);
        } else dst[u] = -1;
    }
    __syncthreads();
    if (tid < 8) lbase[tid] = atomicAdd(&scnt[tid], lcnt[tid]);
    __syncthreads();
    #pragma unroll
    for (int u = 0; u < 8; u++) {
        if (dst[u] >= 0) {
            int st = dst[u] / 6250;
            int gp = st * BK_CAP + lbase[st] + pos[u];
            dstb[gp] = dst[u];
            srcb[gp] = src[u];
        }
    }
}

// ---- pass 2a: striped histogram, reads own segment once ----
__global__ void hist2_kernel(const int* scnt, const int* dstb, int* deg) {
    int stripe = blockIdx.x & 7;
    int bi = blockIdx.x >> 3;
    int cnt = scnt[stripe];
    const int* db = dstb + stripe * BK_CAP;
    for (int t = bi * 256 + threadIdx.x; t < cnt; t += 32 * 256)
        atomicAdd(&deg[db[t]], 1);
}

__global__ void scan1_kernel(const int* deg, int* row_ptr, int* bsum) {
    __shared__ int sh[256];
    int i = blockIdx.x * 256 + threadIdx.x;
    int v = (i < N_NODES) ? deg[i] : 0;
    sh[threadIdx.x] = v;
    __syncthreads();
    for (int off = 1; off < 256; off <<= 1) {
        int t = (threadIdx.x >= off) ? sh[threadIdx.x - off] : 0;
        __syncthreads();
        sh[threadIdx.x] += t;
        __syncthreads();
    }
    if (i < N_NODES) row_ptr[i] = sh[threadIdx.x] - v;
    if (threadIdx.x == 255) bsum[blockIdx.x] = sh[255];
}

__global__ void scan23_kernel(int* row_ptr, int* cursor, const int* bsum) {
    __shared__ int sh[256];
    int t = threadIdx.x;
    int v = (t < 196) ? bsum[t] : 0;
    sh[t] = v;
    __syncthreads();
    for (int off = 1; off < 256; off <<= 1) {
        int u = (t >= off) ? sh[t - off] : 0;
        __syncthreads();
        sh[t] += u;
        __syncthreads();
    }
    int prefix = (blockIdx.x == 0) ? 0 : sh[blockIdx.x - 1];
    int i = blockIdx.x * 256 + t;
    if (i < N_NODES) {
        int r = row_ptr[i] + prefix;
        row_ptr[i] = r;
        cursor[i] = r;
    }
    if (i == 0) row_ptr[N_NODES] = N_ET;
}

// ---- pass 2b: striped scatter, reads own segment once; col writes XCD-local ----
__global__ void scatter2_kernel(const int* scnt, const int* dstb, const int* srcb,
                                int* cursor, int* col) {
    int stripe = blockIdx.x & 7;
    int bi = blockIdx.x >> 3;
    int cnt = scnt[stripe];
    int off = stripe * BK_CAP;
    for (int t = bi * 256 + threadIdx.x; t < cnt; t += 32 * 256) {
        int d = dstb[off + t];
        int pos = atomicAdd(&cursor[d], 1);
        col[pos] = srcb[off + t];
    }
}

// ---- layer 1 gather v3: wave/node; 2 edges/wave, 32 lanes/edge, 4 ch/lane.
// Butterfly 2 stages (4-lane head groups). Masked tails. bf16-packed C out.
__global__ void __launch_bounds__(256) gather1_kernel(
    const int* row_ptr, const int* col, const float* x,
    const float* W1l, const float* b1l, const float* W1r, const float* b1r,
    const float* att, const float* bias, unsigned int* Cb, float* s1r)
{
    int gid = blockIdx.x * 256 + threadIdx.x;
    int n = gid >> 6;
    int lane = threadIdx.x & 63;
    int g = lane >> 5;        // edge slot (0/1)
    int cl = lane & 31;       // channel lane; ch = 4*cl .. +3
    int cb = cl * 4;
    float4 wl0 = *(const float4*)(W1l + cb);
    float4 wl1 = *(const float4*)(W1l + 128 + cb);
    float4 blv = *(const float4*)(b1l + cb);
    float4 atv = *(const float4*)(att + cb);       // pre-scaled by log2e
    float2 xd  = *(const float2*)(x + 2 * n);
    float4 wr0 = *(const float4*)(W1r + cb);
    float4 wr1 = *(const float4*)(W1r + 128 + cb);
    float4 brv = *(const float4*)(b1r + cb);
    float4 xrk;
    xrk.x = fmaf(xd.x, wr0.x, fmaf(xd.y, wr1.x, brv.x));
    xrk.y = fmaf(xd.x, wr0.y, fmaf(xd.y, wr1.y, brv.y));
    xrk.z = fmaf(xd.x, wr0.z, fmaf(xd.y, wr1.z, brv.z));
    xrk.w = fmaf(xd.x, wr0.w, fmaf(xd.y, wr1.w, brv.w));
    int base = __builtin_amdgcn_readfirstlane(row_ptr[n]);
    int deg  = __builtin_amdgcn_readfirstlane(row_ptr[n + 1]) - base;
    float4 acc = make_float4(0.f, 0.f, 0.f, 0.f);
    float den = 0.f;
    for (int j0 = 0; j0 < deg; j0 += 64) {
        int cnt = deg - j0; if (cnt > 64) cnt = 64;
        int msrc = col[base + j0 + lane];   // COL padded by 64: unmasked OK
        for (int j2 = 0; j2 < cnt; j2 += 8) {
            #pragma unroll
            for (int u = 0; u < 4; u++) {
                int e = j2 + 2 * u + g;
                int s = __shfl(msrc, e, 64);       // 2-address broadcast bpermute
                bool valid = e < cnt;
                s = valid ? s : 0;
                float2 xs = *(const float2*)(x + 2 * s);
                float4 xl;
                xl.x = fmaf(xs.x, wl0.x, fmaf(xs.y, wl1.x, blv.x));
                xl.y = fmaf(xs.x, wl0.y, fmaf(xs.y, wl1.y, blv.y));
                xl.z = fmaf(xs.x, wl0.z, fmaf(xs.y, wl1.z, blv.z));
                xl.w = fmaf(xs.x, wl0.w, fmaf(xs.y, wl1.w, blv.w));
                float part = LEAKY(xl.x + xrk.x) * atv.x;
                part = fmaf(LEAKY(xl.y + xrk.y), atv.y, part);
                part = fmaf(LEAKY(xl.z + xrk.z), atv.z, part);
                part = fmaf(LEAKY(xl.w + xrk.w), atv.w, part);
                part += __shfl_xor(part, 1, 64);   // head = 4 lanes
                part += __shfl_xor(part, 2, 64);
                float p = valid ? exp2f(part) : 0.f;
                acc.x = fmaf(p, xl.x, acc.x);
                acc.y = fmaf(p, xl.y, acc.y);
                acc.z = fmaf(p, xl.z, acc.z);
                acc.w = fmaf(p, xl.w, acc.w);
                den += p;
            }
        }
    }
    // cross-edge-group reduce (lane and lane^32 share channels)
    acc.x += __shfl_xor(acc.x, 32, 64);
    acc.y += __shfl_xor(acc.y, 32, 64);
    acc.z += __shfl_xor(acc.z, 32, 64);
    acc.w += __shfl_xor(acc.w, 32, 64);
    den += __shfl_xor(den, 32, 64);
    float inv = 1.f / den;
    float4 bi = *(const float4*)(bias + cb);
    float4 o;
    o.x = fmaf(acc.x, inv, bi.x);
    o.y = fmaf(acc.y, inv, bi.y);
    o.z = fmaf(acc.z, inv, bi.z);
    o.w = fmaf(acc.w, inv, bi.w);
    if (g == 0) {
        uint2 pk;
        pk.x = ((unsigned int)f2bf(o.y) << 16) | f2bf(o.x);
        pk.y = ((unsigned int)f2bf(o.w) << 16) | f2bf(o.z);
        *(uint2*)(Cb + n * 64 + 2 * cl) = pk;
    }
    // ---- fused BN-stats epilogue (4 nodes per block) ----
    __shared__ float sred[4][128];
    __shared__ float qred[4][128];
    int wv = threadIdx.x >> 6;
    if (g == 0) {
        sred[wv][cb]     = o.x; qred[wv][cb]     = o.x * o.x;
        sred[wv][cb + 1] = o.y; qred[wv][cb + 1] = o.y * o.y;
        sred[wv][cb + 2] = o.z; qred[wv][cb + 2] = o.z * o.z;
        sred[wv][cb + 3] = o.w; qred[wv][cb + 3] = o.w * o.w;
    }
    __syncthreads();
    int t = threadIdx.x;
    float a;
    if (t < 128) a = sred[0][t] + sred[1][t] + sred[2][t] + sred[3][t];
    else { int c = t - 128; a = qred[0][c] + qred[1][c] + qred[2][c] + qred[3][c]; }
    atomicAdd(&s1r[(blockIdx.x & 63) * 256 + t], a);
}

// ---- replica reduce ----
__global__ void red1_kernel(const float* s1r, float* stats) {
    int t = threadIdx.x;
    int r0 = blockIdx.x * 8;
    float a = 0.f;
    #pragma unroll
    for (int r = 0; r < 8; r++) a += s1r[(r0 + r) * 256 + t];
    atomicAdd(&stats[t], a);
}

// ---- layer 2 linear, register-tiled, fused BN1+ELU on staging (bf16 C in).
// xl2 written as bf16 (gather2's random-gather table); xr2 stays f32.
__global__ void __launch_bounds__(256) lin2_kernel(
    const unsigned int* Cb, const float* stats, const float* g1, const float* be1,
    const float* Wl, const float* bl, const float* Wr, const float* br,
    unsigned short* xl2b, float* xr2)
{
    __shared__ float h[64 * 132];
    int tid = threadIdx.x;
    int nb = blockIdx.x * 64;
    for (int i = tid; i < 64 * 64; i += 256) {      // uint = 2 bf16 channels
        int ni = i >> 6, kp = i & 63;
        int n = nb + ni;
        int k = 2 * kp;
        float v0 = 0.f, v1 = 0.f;
        if (n < N_NODES) {
            unsigned int pk = Cb[n * 64 + kp];
            float val0 = __uint_as_float(pk << 16);
            float val1 = __uint_as_float(pk & 0xffff0000u);
            float mu0 = stats[k] * (1.0f / N_NODES);
            float var0 = stats[128 + k] * (1.0f / N_NODES) - mu0 * mu0;
            float sc0 = g1[k] * rsqrtf(var0 + EPSBN);
            float b0 = (val0 - mu0) * sc0 + be1[k];
            v0 = b0 > 0.f ? b0 : __expf(b0) - 1.f;   // ELU
            float mu1 = stats[k + 1] * (1.0f / N_NODES);
            float var1 = stats[128 + k + 1] * (1.0f / N_NODES) - mu1 * mu1;
            float sc1 = g1[k + 1] * rsqrtf(var1 + EPSBN);
            float b1 = (val1 - mu1) * sc1 + be1[k + 1];
            v1 = b1 > 0.f ? b1 : __expf(b1) - 1.f;
        }
        h[ni * 132 + k]     = v0;
        h[ni * 132 + k + 1] = v1;
    }
    __syncthreads();
    int kt = (tid & 15) * 4;
    int nt = (tid >> 4) * 4;
    float accl[4][4], accr[4][4];
    #pragma unroll
    for (int i = 0; i < 4; i++) {
        #pragma unroll
        for (int k = 0; k < 4; k++) { accl[i][k] = 0.f; accr[i][k] = 0.f; }
    }
    for (int j = 0; j < 128; j += 4) {
        float4 hv[4];
        #pragma unroll
        for (int i = 0; i < 4; i++)
            hv[i] = *(const float4*)&h[(nt + i) * 132 + j];
        #pragma unroll
        for (int jj = 0; jj < 4; jj++) {
            float4 wl4 = *(const float4*)&Wl[(j + jj) * 64 + kt];
            float4 wr4 = *(const float4*)&Wr[(j + jj) * 64 + kt];
            #pragma unroll
            for (int i = 0; i < 4; i++) {
                float hvv = (jj == 0) ? hv[i].x : (jj == 1) ? hv[i].y :
                            (jj == 2) ? hv[i].z : hv[i].w;
                accl[i][0] += hvv * wl4.x; accl[i][1] += hvv * wl4.y;
                accl[i][2] += hvv * wl4.z; accl[i][3] += hvv * wl4.w;
                accr[i][0] += hvv * wr4.x; accr[i][1] += hvv * wr4.y;
                accr[i][2] += hvv * wr4.z; accr[i][3] += hvv * wr4.w;
            }
        }
    }
    float4 blv = *(const float4*)&bl[kt];
    float4 brv = *(const float4*)&br[kt];
    #pragma unroll
    for (int i = 0; i < 4; i++) {
        int n = nb + nt + i;
        if (n < N_NODES) {
            ushort4 ob;
            ob.x = f2bf(accl[i][0] + blv.x);
            ob.y = f2bf(accl[i][1] + blv.y);
            ob.z = f2bf(accl[i][2] + blv.z);
            ob.w = f2bf(accl[i][3] + blv.w);
            *(ushort4*)&xl2b[n * 64 + kt] = ob;
            float4 o;
            o.x = accr[i][0] + brv.x; o.y = accr[i][1] + brv.y;
            o.z = accr[i][2] + brv.z; o.w = accr[i][3] + brv.w;
            *(float4*)&xr2[n * 64 + kt] = o;
        }
    }
}

// ---- layer 2 gather: 4 edges/wave, 16 lanes/edge, 4 bf16 ch/lane ----
__global__ void __launch_bounds__(256) gather2_kernel(
    const int* row_ptr, const int* col, const unsigned short* xl2b, const float* xr2,
    const float* att, const float* bias, float* C, float* s2r)
{
    int gid = blockIdx.x * 256 + threadIdx.x;
    int n = gid >> 6;
    int lane = threadIdx.x & 63;
    int grp = lane >> 4;       // edge slot (0..3)
    int cidx = lane & 15;      // ch = 4*cidx .. +3
    float4 xrv = *(const float4*)(xr2 + n * 64 + 4 * cidx);
    float4 atv = *(const float4*)(att + 4 * cidx);   // pre-scaled by log2e
    int base = __builtin_amdgcn_readfirstlane(row_ptr[n]);
    int deg  = __builtin_amdgcn_readfirstlane(row_ptr[n + 1]) - base;
    float4 acc = make_float4(0.f, 0.f, 0.f, 0.f);
    float den = 0.f;
    for (int j0 = 0; j0 < deg; j0 += 64) {
        int cnt = deg - j0; if (cnt > 64) cnt = 64;
        int msrc = col[base + j0 + lane];
        for (int j4 = 0; j4 < cnt; j4 += 8) {
            int e0 = j4 + grp, e1 = j4 + 4 + grp;
            int s0 = __shfl(msrc, e0, 64);
            int s1 = __shfl(msrc, e1, 64);
            bool v0 = e0 < cnt, v1 = e1 < cnt;
            s0 = v0 ? s0 : 0;
            s1 = v1 ? s1 : 0;
            uint2 ba = *(const uint2*)(xl2b + (size_t)s0 * 64 + 4 * cidx);
            uint2 bb = *(const uint2*)(xl2b + (size_t)s1 * 64 + 4 * cidx);
            float a0 = __uint_as_float(ba.x << 16);
            float a1 = __uint_as_float(ba.x & 0xffff0000u);
            float a2 = __uint_as_float(ba.y << 16);
            float a3 = __uint_as_float(ba.y & 0xffff0000u);
            float b0 = __uint_as_float(bb.x << 16);
            float b1 = __uint_as_float(bb.x & 0xffff0000u);
            float b2 = __uint_as_float(bb.y << 16);
            float b3 = __uint_as_float(bb.y & 0xffff0000u);
            float pa = LEAKY(a0 + xrv.x) * atv.x;
            pa = fmaf(LEAKY(a1 + xrv.y), atv.y, pa);
            pa = fmaf(LEAKY(a2 + xrv.z), atv.z, pa);
            pa = fmaf(LEAKY(a3 + xrv.w), atv.w, pa);
            float pb = LEAKY(b0 + xrv.x) * atv.x;
            pb = fmaf(LEAKY(b1 + xrv.y), atv.y, pb);
            pb = fmaf(LEAKY(b2 + xrv.z), atv.z, pb);
            pb = fmaf(LEAKY(b3 + xrv.w), atv.w, pb);
            pa += __shfl_xor(pa, 1, 64);    // head = 4 lanes
            pa += __shfl_xor(pa, 2, 64);
            pb += __shfl_xor(pb, 1, 64);
            pb += __shfl_xor(pb, 2, 64);
            float ea = v0 ? exp2f(pa) : 0.f;
            float eb = v1 ? exp2f(pb) : 0.f;
            acc.x = fmaf(ea, a0, acc.x); acc.x = fmaf(eb, b0, acc.x);
            acc.y = fmaf(ea, a1, acc.y); acc.y = fmaf(eb, b1, acc.y);
            acc.z = fmaf(ea, a2, acc.z); acc.z = fmaf(eb, b2, acc.z);
            acc.w = fmaf(ea, a3, acc.w); acc.w = fmaf(eb, b3, acc.w);
            den += ea + eb;
        }
    }
    acc.x += __shfl_xor(acc.x, 16, 64); acc.x += __shfl_xor(acc.x, 32, 64);
    acc.y += __shfl_xor(acc.y, 16, 64); acc.y += __shfl_xor(acc.y, 32, 64);
    acc.z += __shfl_xor(acc.z, 16, 64); acc.z += __shfl_xor(acc.z, 32, 64);
    acc.w += __shfl_xor(acc.w, 16, 64); acc.w += __shfl_xor(acc.w, 32, 64);
    den += __shfl_xor(den, 16, 64);
    den += __shfl_xor(den, 32, 64);
    float inv = 1.f / den;
    float4 bi = *(const float4*)(bias + 4 * cidx);
    float4 o;
    o.x = fmaf(acc.x, inv, bi.x);
    o.y = fmaf(acc.y, inv, bi.y);
    o.z = fmaf(acc.z, inv, bi.z);
    o.w = fmaf(acc.w, inv, bi.w);
    if (lane < 16) *(float4*)(C + n * 64 + 4 * cidx) = o;
    // ---- fused BN-stats epilogue ----
    __shared__ float sred[4][64];
    __shared__ float qred[4][64];
    int wv = threadIdx.x >> 6;
    if (lane < 16) {
        int c = 4 * cidx;
        sred[wv][c]     = o.x; qred[wv][c]     = o.x * o.x;
        sred[wv][c + 1] = o.y; qred[wv][c + 1] = o.y * o.y;
        sred[wv][c + 2] = o.z; qred[wv][c + 2] = o.z * o.z;
        sred[wv][c + 3] = o.w; qred[wv][c + 3] = o.w * o.w;
    }
    __syncthreads();
    int t = threadIdx.x;
    if (t < 128) {
        float a;
        if (t < 64) a = sred[0][t] + sred[1][t] + sred[2][t] + sred[3][t];
        else { int c = t - 64; a = qred[0][c] + qred[1][c] + qred[2][c] + qred[3][c]; }
        atomicAdd(&s2r[(blockIdx.x & 63) * 128 + t], a);
    }
}

__global__ void red2_kernel(const float* s2r, float* stats) {
    int t = threadIdx.x;   // 128 threads
    int r0 = blockIdx.x * 8;
    float a = 0.f;
    #pragma unroll
    for (int r = 0; r < 8; r++) a += s2r[(r0 + r) * 128 + t];
    atomicAdd(&stats[t], a);
}

// ---- layer 3 linear: wave/node butterfly reduce, fused BN2+ELU ----
__global__ void __launch_bounds__(256) lin3_kernel(
    const float* C, const float* stats2, const float* g2, const float* be2,
    const float* Wl, const float* bl, const float* Wr, const float* br,
    float* xl3, float* xr3)
{
    int gid = blockIdx.x * 256 + threadIdx.x;
    int n = gid >> 6;
    int lane = threadIdx.x & 63;
    if (n >= N_NODES) return;
    float mu = stats2[lane] * (1.0f / N_NODES);
    float var = stats2[64 + lane] * (1.0f / N_NODES) - mu * mu;
    float sc = g2[lane] * rsqrtf(var + EPSBN);
    float of = be2[lane] - mu * sc;
    float v = C[n * 64 + lane] * sc + of;
    float h = v > 0.f ? v : __expf(v) - 1.f;   // ELU
    float2 wlv = *(const float2*)(Wl + 2 * lane);
    float2 wrv = *(const float2*)(Wr + 2 * lane);
    float a0 = h * wlv.x, a1 = h * wlv.y;
    float r0 = h * wrv.x, r1 = h * wrv.y;
    #pragma unroll
    for (int m = 1; m < 64; m <<= 1) {
        a0 += __shfl_xor(a0, m, 64);
        a1 += __shfl_xor(a1, m, 64);
        r0 += __shfl_xor(r0, m, 64);
        r1 += __shfl_xor(r1, m, 64);
    }
    if (lane == 0) {
        xl3[2 * n]     = a0 + bl[0];
        xl3[2 * n + 1] = a1 + bl[1];
        xr3[2 * n]     = r0 + br[0];
        xr3[2 * n + 1] = r1 + br[1];
    }
}

// ---- layer 3 gather: H=1, C=2; 4 lanes/node, fused output ----
__global__ void __launch_bounds__(256) gather3_kernel(
    const int* row_ptr, const int* col,
    const float* xl3, const float* xr3,
    const float* att, const float* bias,
    void* out, const int* flags) {
    int gid = blockIdx.x * 256 + threadIdx.x;
    int n = gid >> 2;                  // 4 lanes per node
    int q = threadIdx.x & 3;
    if (n >= N_NODES) return;
    float a0 = att[0], a1 = att[1];    // pre-scaled by log2e
    float xr0 = xr3[2 * n], xr1 = xr3[2 * n + 1];
    float acc0 = 0.f, acc1 = 0.f, den = 0.f;
    int e0 = row_ptr[n], e1 = row_ptr[n + 1];
    for (int e = e0 + q; e < e1; e += 4) {
        int src = col[e];
        float2 xs = *(const float2*)(xl3 + 2 * src);
        float z0 = LEAKY(xs.x + xr0);
        float z1 = LEAKY(xs.y + xr1);
        float p = exp2f(fmaf(z0, a0, z1 * a1));
        acc0 = fmaf(p, xs.x, acc0);
        acc1 = fmaf(p, xs.y, acc1);
        den += p;
    }
    acc0 += __shfl_xor(acc0, 1, 64); acc0 += __shfl_xor(acc0, 2, 64);
    acc1 += __shfl_xor(acc1, 1, 64); acc1 += __shfl_xor(acc1, 2, 64);
    den  += __shfl_xor(den, 1, 64);  den  += __shfl_xor(den, 2, 64);
    if (q == 0) {
        float inv = 1.f / den;
        float v0 = fmaf(acc0, inv, bias[0]);
        float v1 = fmaf(acc1, inv, bias[1]);
        if (flags[0]) {
            ((float*)out)[2 * n] = v0;
            ((float*)out)[2 * n + 1] = v1;
        } else {
            ((__hip_bfloat16*)out)[2 * n] = __float2bfloat16(v0);
            ((__hip_bfloat16*)out)[2 * n + 1] = __float2bfloat16(v1);
        }
    }
}

extern "C" void kernel_launch(void* const* d_in, const int* in_sizes, int n_in,
                              void* d_out, int out_size, void* d_ws, size_t ws_size,
                              hipStream_t stream) {
    float* W = (float*)d_ws;
    float* C = W + OFF_C;
    float* A = W + OFF_A;
    float* B = W + OFF_B;
    float* STATS = W + OFF_STATS;
    float* S1R = W + OFF_S1R;
    float* S2R = W + OFF_S2R;
    float* P = W + OFF_P;
    int* ROWPTR = (int*)(W + OFF_ROWPTR);
    int* DEG    = (int*)(W + OFF_DEG);
    int* CURSOR = (int*)(W + OFF_CURSOR);
    int* BSUM   = (int*)(W + OFF_BSUM);
    int* COL    = (int*)(W + OFF_COL);
    int* FLAGS  = (int*)(W + OFF_FLAGS);
    int* SCNT   = (int*)(W + OFF_SCNT);
    // bucket segments overlay the C region (C first written by gather1)
    int* DSTB   = (int*)(W + OFF_C);
    int* SRCB   = DSTB + 8 * BK_CAP;

    const int* ei = (const int*)d_in[1];

    float* Px  = P;
    float* W1l = Px + 100000; float* b1l = W1l + 256; float* W1r = b1l + 128; float* b1r = W1r + 256;
    float* a1  = b1r + 128;   float* bias1 = a1 + 128; float* g1 = bias1 + 128; float* be1 = g1 + 128;
    float* W2l = be1 + 128;   float* b2l = W2l + 8192; float* W2r = b2l + 64;  float* b2r = W2r + 8192;
    float* a2  = b2r + 64;    float* bias2 = a2 + 64;  float* g2 = bias2 + 64; float* be2 = g2 + 64;
    float* W3l = be2 + 64;    float* b3l = W3l + 128;  float* W3r = b3l + 2;   float* b3r = W3r + 128;
    float* a3  = b3r + 2;     float* bias3 = a3 + 2;

    prep_kernel<<<196, 256, 0, stream>>>((const unsigned short*)d_in[0], ei, FLAGS, DEG, STATS, S1R, S2R, SCNT);

    ParamPtrs ps;
    ps.p[0] = d_in[0];
    for (int j = 1; j < 23; j++) ps.p[j] = d_in[j + 1];
    convert_kernel<<<(N_PARAM_TOT + 255) / 256, 256, 0, stream>>>(ps, P, FLAGS);

    // ---- CSR build: read-once bucketing, then striped 1x-read hist/scatter ----
    bucket_kernel<<<(N_ET + BK_CHUNK - 1) / BK_CHUNK, 256, 0, stream>>>(ei, FLAGS, SCNT, DSTB, SRCB);
    hist2_kernel<<<256, 256, 0, stream>>>(SCNT, DSTB, DEG);
    scan1_kernel<<<196, 256, 0, stream>>>(DEG, ROWPTR, BSUM);
    scan23_kernel<<<196, 256, 0, stream>>>(ROWPTR, CURSOR, BSUM);
    scatter2_kernel<<<256, 256, 0, stream>>>(SCNT, DSTB, SRCB, CURSOR, COL);

    // ---- layer 1 (BN stats fused into gather epilogue; bf16 C table) ----
    gather1_kernel<<<N_NODES * 64 / 256, 256, 0, stream>>>(ROWPTR, COL, Px, W1l, b1l, W1r, b1r, a1, bias1, (unsigned int*)C, S1R);
    red1_kernel<<<8, 256, 0, stream>>>(S1R, STATS);

    // ---- layer 2 (BN1+ELU fused into lin2 staging; bf16 xl2 table; stats fused) ----
    lin2_kernel<<<(N_NODES + 63) / 64, 256, 0, stream>>>((const unsigned int*)C, STATS, g1, be1, W2l, b2l, W2r, b2r, (unsigned short*)A, B);
    gather2_kernel<<<N_NODES * 64 / 256, 256, 0, stream>>>(ROWPTR, COL, (const unsigned short*)A, B, a2, bias2, C, S2R);
    red2_kernel<<<8, 128, 0, stream>>>(S2R, STATS + 256);

    // ---- layer 3 (BN2+ELU fused into lin3) ----
    lin3_kernel<<<N_NODES * 64 / 256, 256, 0, stream>>>(C, STATS + 256, g2, be2, W3l, b3l, W3r, b3r, A, B);
    gather3_kernel<<<(N_NODES * 4 + 255) / 256, 256, 0, stream>>>(ROWPTR, COL, A, B, a3, bias3, d_out, FLAGS);
}

// Round 14
// 335.826 us; speedup vs baseline: 1.0131x; 1.0131x over previous
//
#include <hip/hip_runtime.h>
#include <hip/hip_bf16.h>

#define N_NODES 50000
#define N_E0    800000
#define N_ET    850000
#define EPSBN   1e-5f
#define LOG2E   1.4426950408889634f

#define LEAKY(z) fmaxf((z), 0.2f * (z))

// ---- workspace layout (32-bit word offsets) ----
#define OFF_C 0                 // layer1 C bf16-packed (64N words); overlaid by DSTB/SRCB during CSR build; layer2 C f32
#define OFF_A (128*N_NODES)     // xl2b (bf16) / xl3
#define OFF_B (192*N_NODES)     // xr2 (f32) / xr3
#define OFF_STATS (256*N_NODES)
#define OFF_S1R (OFF_STATS + 512)            // 64 replicas x 256
#define OFF_S2R (OFF_S1R + 16384)            // 64 replicas x 128
#define OFF_P (OFF_S2R + 8192)
#define N_PARAM_TOT 118312
#define OFF_ROWPTR (OFF_P + N_PARAM_TOT)      // 50001 ints
#define OFF_DEG    (OFF_ROWPTR + 50001)       // 50000 ints
#define OFF_CURSOR (OFF_DEG + 50000)          // 50000 ints
#define OFF_BSUM   (OFF_CURSOR + 50000)       // 256 ints
#define OFF_COL    (OFF_BSUM + 256)           // 850000 + 64 pad ints
#define OFF_FLAGS  (OFF_COL + 850064)         // 2 ints
#define OFF_SCNT   (OFF_FLAGS + 2)            // 8 stripe cursors

// per-stripe bucket segments, overlaid on the C region (C written later)
#define BK_CAP 131072
#define BK_CHUNK 2048

__device__ __forceinline__ float bf2f(unsigned short u) {
    return __uint_as_float(((unsigned int)u) << 16);
}
__device__ __forceinline__ unsigned short f2bf(float f) {
    unsigned int u = __float_as_uint(f);
    u += 0x7FFFu + ((u >> 16) & 1u);    // round-to-nearest-even
    return (unsigned short)(u >> 16);
}

// ---- prep: dtype detect (block 0) + deg/stats/replica/scnt init ----
__global__ void prep_kernel(const unsigned short* xr, const int* ei, int* flags,
                            int* deg, float* stats, float* s1r, float* s2r, int* scnt) {
    int i = blockIdx.x * 256 + threadIdx.x;
    if (i < N_NODES) deg[i] = 0;   // counted in bucket_kernel
    if (i < 512) stats[i] = 0.f;
    if (i < 16384) s1r[i] = 0.f;
    if (i < 8192)  s2r[i] = 0.f;
    if (i < 8) scnt[i] = 0;
    if (blockIdx.x == 0) {
        __shared__ int c1, c2;
        if (threadIdx.x == 0) { c1 = 0; c2 = 0; }
        __syncthreads();
        int t = threadIdx.x;
        int l1 = 0, l2 = 0;
        for (int k = t; k < 2048; k += 256) {
            float v = bf2f(xr[k]);
            if (!(fabsf(v) <= 100.0f)) l1++;
            if (ei[2 * k + 1] != 0) l2++;
        }
        atomicAdd(&c1, l1);
        atomicAdd(&c2, l2);
        __syncthreads();
        if (t == 0) {
            flags[0] = (c1 > 16) ? 1 : 0;   // 1 => inputs are f32
            flags[1] = (c2 == 0) ? 1 : 0;   // 1 => edge_index is int64
        }
    }
}

struct ParamPtrs { const void* p[23]; };

// stage f32 params; att vectors (t=5,13,21) pre-scaled by log2e so softmax uses exp2
__global__ void convert_kernel(ParamPtrs ps, float* dst, const int* flags) {
    const int sizes[23] = {100000, 256,128,256,128,128,128,128,128,
                           8192,64,8192,64,64,64,64,64,
                           128,2,128,2,2,2};
    int g = blockIdx.x * 256 + threadIdx.x;
    if (g >= N_PARAM_TOT) return;
    int t = 0, off = g;
    while (off >= sizes[t]) { off -= sizes[t]; t++; }
    float v;
    if (flags[0]) v = ((const float*)ps.p[t])[off];
    else          v = bf2f(((const unsigned short*)ps.p[t])[off]);
    if (t == 5 || t == 13 || t == 21) v *= LOG2E;
    dst[g] = v;
}

// ---- pass 1: read edges ONCE; bucket (dst,src) into 8 stripes AND count deg ----
__global__ void bucket_kernel(const int* ei, const int* flags, int* scnt,
                              int* dstb, int* srcb, int* deg) {
    __shared__ int lcnt[8];
    __shared__ int lbase[8];
    int tid = threadIdx.x;
    if (tid < 8) lcnt[tid] = 0;
    __syncthreads();
    int base_e = blockIdx.x * BK_CHUNK;
    int i64 = flags[1];
    int src[8], dst[8], pos[8];
    #pragma unroll
    for (int u = 0; u < 8; u++) {
        int e = base_e + u * 256 + tid;
        if (e < N_ET) {
            int s, d;
            if (e < N_E0) {
                d = i64 ? ei[2 * (N_E0 + e)] : ei[N_E0 + e];
                s = i64 ? ei[2 * e] : ei[e];
            } else { s = d = e - N_E0; }
            src[u] = s; dst[u] = d;
            pos[u] = atomicAdd(&lcnt[d / 6250], 1);
            atomicAdd(&deg[d], 1);           // fused histogram (was hist2_kernel)
        } else dst[u] = -1;
    }
    __syncthreads();
    if (tid < 8) lbase[tid] = atomicAdd(&scnt[tid], lcnt[tid]);
    __syncthreads();
    #pragma unroll
    for (int u = 0; u < 8; u++) {
        if (dst[u] >= 0) {
            int st = dst[u] / 6250;
            int gp = st * BK_CAP + lbase[st] + pos[u];
            dstb[gp] = dst[u];
            srcb[gp] = src[u];
        }
    }
}

__global__ void scan1_kernel(const int* deg, int* row_ptr, int* bsum) {
    __shared__ int sh[256];
    int i = blockIdx.x * 256 + threadIdx.x;
    int v = (i < N_NODES) ? deg[i] : 0;
    sh[threadIdx.x] = v;
    __syncthreads();
    for (int off = 1; off < 256; off <<= 1) {
        int t = (threadIdx.x >= off) ? sh[threadIdx.x - off] : 0;
        __syncthreads();
        sh[threadIdx.x] += t;
        __syncthreads();
    }
    if (i < N_NODES) row_ptr[i] = sh[threadIdx.x] - v;
    if (threadIdx.x == 255) bsum[blockIdx.x] = sh[255];
}

__global__ void scan23_kernel(int* row_ptr, int* cursor, const int* bsum) {
    __shared__ int sh[256];
    int t = threadIdx.x;
    int v = (t < 196) ? bsum[t] : 0;
    sh[t] = v;
    __syncthreads();
    for (int off = 1; off < 256; off <<= 1) {
        int u = (t >= off) ? sh[t - off] : 0;
        __syncthreads();
        sh[t] += u;
        __syncthreads();
    }
    int prefix = (blockIdx.x == 0) ? 0 : sh[blockIdx.x - 1];
    int i = blockIdx.x * 256 + t;
    if (i < N_NODES) {
        int r = row_ptr[i] + prefix;
        row_ptr[i] = r;
        cursor[i] = r;
    }
    if (i == 0) row_ptr[N_NODES] = N_ET;
}

// ---- pass 2: striped scatter, reads own segment once; col writes XCD-local ----
__global__ void scatter2_kernel(const int* scnt, const int* dstb, const int* srcb,
                                int* cursor, int* col) {
    int stripe = blockIdx.x & 7;
    int bi = blockIdx.x >> 3;
    int cnt = scnt[stripe];
    int off = stripe * BK_CAP;
    for (int t = bi * 256 + threadIdx.x; t < cnt; t += 32 * 256) {
        int d = dstb[off + t];
        int pos = atomicAdd(&cursor[d], 1);
        col[pos] = srcb[off + t];
    }
}

// ---- layer 1 gather (round-12 measured-best form): wave/node, 2ch/lane,
// unroll-8, readlane scalar-broadcast path. bf16-packed C out.
__global__ void __launch_bounds__(256) gather1_kernel(
    const int* row_ptr, const int* col, const float* x,
    const float* W1l, const float* b1l, const float* W1r, const float* b1r,
    const float* att, const float* bias, unsigned int* Cb, float* s1r)
{
    int gid = blockIdx.x * 256 + threadIdx.x;
    int n = gid >> 6;
    int lane = threadIdx.x & 63;
    float2 wl0 = *(const float2*)(W1l + 2 * lane);
    float2 wl1 = *(const float2*)(W1l + 128 + 2 * lane);
    float2 bl  = *(const float2*)(b1l + 2 * lane);
    float2 wr0 = *(const float2*)(W1r + 2 * lane);
    float2 wr1 = *(const float2*)(W1r + 128 + 2 * lane);
    float2 br  = *(const float2*)(b1r + 2 * lane);
    float2 at  = *(const float2*)(att + 2 * lane);   // pre-scaled by log2e
    float2 xd  = *(const float2*)(x + 2 * n);
    float xr0 = fmaf(xd.x, wr0.x, fmaf(xd.y, wr1.x, br.x));
    float xr1 = fmaf(xd.x, wr0.y, fmaf(xd.y, wr1.y, br.y));
    int base = __builtin_amdgcn_readfirstlane(row_ptr[n]);
    int deg  = __builtin_amdgcn_readfirstlane(row_ptr[n + 1]) - base;
    float acc0 = 0.f, acc1 = 0.f, den = 0.f;
    for (int j0 = 0; j0 < deg; j0 += 64) {
        int cnt = deg - j0; if (cnt > 64) cnt = 64;
        int msrc = col[base + j0 + lane];   // COL padded by 64: unmasked OK
        int j = 0;
        for (; j + 8 <= cnt; j += 8) {
            int s[8];
            #pragma unroll
            for (int u = 0; u < 8; u++) s[u] = __builtin_amdgcn_readlane(msrc, j + u);
            float2 xs[8];
            #pragma unroll
            for (int u = 0; u < 8; u++) xs[u] = *(const float2*)(x + 2 * s[u]);
            float xl0[8], xl1[8], part[8];
            #pragma unroll
            for (int u = 0; u < 8; u++) {
                xl0[u] = fmaf(xs[u].x, wl0.x, fmaf(xs[u].y, wl1.x, bl.x));
                xl1[u] = fmaf(xs[u].x, wl0.y, fmaf(xs[u].y, wl1.y, bl.y));
                float z0 = LEAKY(xl0[u] + xr0);
                float z1 = LEAKY(xl1[u] + xr1);
                part[u] = fmaf(z0, at.x, z1 * at.y);
            }
            #pragma unroll
            for (int m = 1; m <= 4; m <<= 1) {
                #pragma unroll
                for (int u = 0; u < 8; u++) part[u] += __shfl_xor(part[u], m, 64);
            }
            #pragma unroll
            for (int u = 0; u < 8; u++) {
                float p = exp2f(part[u]);
                acc0 = fmaf(p, xl0[u], acc0);
                acc1 = fmaf(p, xl1[u], acc1);
                den += p;
            }
        }
        for (; j < cnt; ++j) {
            int s0 = __builtin_amdgcn_readlane(msrc, j);
            float2 xs = *(const float2*)(x + 2 * s0);
            float xl0s = fmaf(xs.x, wl0.x, fmaf(xs.y, wl1.x, bl.x));
            float xl1s = fmaf(xs.x, wl0.y, fmaf(xs.y, wl1.y, bl.y));
            float z0 = LEAKY(xl0s + xr0);
            float z1 = LEAKY(xl1s + xr1);
            float part = fmaf(z0, at.x, z1 * at.y);
            part += __shfl_xor(part, 1, 64);
            part += __shfl_xor(part, 2, 64);
            part += __shfl_xor(part, 4, 64);
            float p = exp2f(part);
            acc0 = fmaf(p, xl0s, acc0);
            acc1 = fmaf(p, xl1s, acc1);
            den += p;
        }
    }
    float inv = 1.f / den;
    float2 bi = *(const float2*)(bias + 2 * lane);
    float2 outv;
    outv.x = fmaf(acc0, inv, bi.x);
    outv.y = fmaf(acc1, inv, bi.y);
    Cb[n * 64 + lane] = ((unsigned int)f2bf(outv.y) << 16) | f2bf(outv.x);
    // ---- fused BN-stats epilogue (4 nodes per block) ----
    __shared__ float sred[4][128];
    __shared__ float qred[4][128];
    int wv = threadIdx.x >> 6;
    sred[wv][2 * lane]     = outv.x;
    sred[wv][2 * lane + 1] = outv.y;
    qred[wv][2 * lane]     = outv.x * outv.x;
    qred[wv][2 * lane + 1] = outv.y * outv.y;
    __syncthreads();
    int t = threadIdx.x;
    float a;
    if (t < 128) a = sred[0][t] + sred[1][t] + sred[2][t] + sred[3][t];
    else { int c = t - 128; a = qred[0][c] + qred[1][c] + qred[2][c] + qred[3][c]; }
    atomicAdd(&s1r[(blockIdx.x & 63) * 256 + t], a);
}

// ---- replica reduce + BN coefficient finalize (layer 1): single block.
// Writes stats[k]=scale, stats[128+k]=offset so lin2 staging is 1 fma.
__global__ void red1_kernel(const float* s1r, const float* g1, const float* be1,
                            float* stats) {
    __shared__ float ls[256];
    int t = threadIdx.x;
    float a = 0.f;
    for (int r = 0; r < 64; r++) a += s1r[r * 256 + t];
    ls[t] = a;
    __syncthreads();
    if (t < 128) {
        float mu = ls[t] * (1.0f / N_NODES);
        float var = ls[128 + t] * (1.0f / N_NODES) - mu * mu;
        float sc = g1[t] * rsqrtf(var + EPSBN);
        stats[t] = sc;
        stats[128 + t] = be1[t] - mu * sc;
    }
}

// ---- layer 2 linear, register-tiled, fused BN1+ELU on staging (bf16 C in).
// xl2 written as bf16 (gather2's random-gather table); xr2 stays f32.
__global__ void __launch_bounds__(256) lin2_kernel(
    const unsigned int* Cb, const float* stats, const float* Wl, const float* bl,
    const float* Wr, const float* br, unsigned short* xl2b, float* xr2)
{
    __shared__ float h[64 * 132];
    int tid = threadIdx.x;
    int nb = blockIdx.x * 64;
    for (int i = tid; i < 64 * 64; i += 256) {      // uint = 2 bf16 channels
        int ni = i >> 6, kp = i & 63;
        int n = nb + ni;
        int k = 2 * kp;
        float v0 = 0.f, v1 = 0.f;
        if (n < N_NODES) {
            unsigned int pk = Cb[n * 64 + kp];
            float b0 = fmaf(__uint_as_float(pk << 16),        stats[k],     stats[128 + k]);
            float b1 = fmaf(__uint_as_float(pk & 0xffff0000u), stats[k + 1], stats[128 + k + 1]);
            v0 = b0 > 0.f ? b0 : __expf(b0) - 1.f;   // ELU
            v1 = b1 > 0.f ? b1 : __expf(b1) - 1.f;
        }
        h[ni * 132 + k]     = v0;
        h[ni * 132 + k + 1] = v1;
    }
    __syncthreads();
    int kt = (tid & 15) * 4;
    int nt = (tid >> 4) * 4;
    float accl[4][4], accr[4][4];
    #pragma unroll
    for (int i = 0; i < 4; i++) {
        #pragma unroll
        for (int k = 0; k < 4; k++) { accl[i][k] = 0.f; accr[i][k] = 0.f; }
    }
    for (int j = 0; j < 128; j += 4) {
        float4 hv[4];
        #pragma unroll
        for (int i = 0; i < 4; i++)
            hv[i] = *(const float4*)&h[(nt + i) * 132 + j];
        #pragma unroll
        for (int jj = 0; jj < 4; jj++) {
            float4 wl4 = *(const float4*)&Wl[(j + jj) * 64 + kt];
            float4 wr4 = *(const float4*)&Wr[(j + jj) * 64 + kt];
            #pragma unroll
            for (int i = 0; i < 4; i++) {
                float hvv = (jj == 0) ? hv[i].x : (jj == 1) ? hv[i].y :
                            (jj == 2) ? hv[i].z : hv[i].w;
                accl[i][0] += hvv * wl4.x; accl[i][1] += hvv * wl4.y;
                accl[i][2] += hvv * wl4.z; accl[i][3] += hvv * wl4.w;
                accr[i][0] += hvv * wr4.x; accr[i][1] += hvv * wr4.y;
                accr[i][2] += hvv * wr4.z; accr[i][3] += hvv * wr4.w;
            }
        }
    }
    float4 blv = *(const float4*)&bl[kt];
    float4 brv = *(const float4*)&br[kt];
    #pragma unroll
    for (int i = 0; i < 4; i++) {
        int n = nb + nt + i;
        if (n < N_NODES) {
            ushort4 ob;
            ob.x = f2bf(accl[i][0] + blv.x);
            ob.y = f2bf(accl[i][1] + blv.y);
            ob.z = f2bf(accl[i][2] + blv.z);
            ob.w = f2bf(accl[i][3] + blv.w);
            *(ushort4*)&xl2b[n * 64 + kt] = ob;
            float4 o;
            o.x = accr[i][0] + brv.x; o.y = accr[i][1] + brv.y;
            o.z = accr[i][2] + brv.z; o.w = accr[i][3] + brv.w;
            *(float4*)&xr2[n * 64 + kt] = o;
        }
    }
}

// ---- layer 2 gather: 4 edges/wave, 16 lanes/edge, 4 bf16 ch/lane ----
__global__ void __launch_bounds__(256) gather2_kernel(
    const int* row_ptr, const int* col, const unsigned short* xl2b, const float* xr2,
    const float* att, const float* bias, float* C, float* s2r)
{
    int gid = blockIdx.x * 256 + threadIdx.x;
    int n = gid >> 6;
    int lane = threadIdx.x & 63;
    int grp = lane >> 4;       // edge slot (0..3)
    int cidx = lane & 15;      // ch = 4*cidx .. +3
    float4 xrv = *(const float4*)(xr2 + n * 64 + 4 * cidx);
    float4 atv = *(const float4*)(att + 4 * cidx);   // pre-scaled by log2e
    int base = __builtin_amdgcn_readfirstlane(row_ptr[n]);
    int deg  = __builtin_amdgcn_readfirstlane(row_ptr[n + 1]) - base;
    float4 acc = make_float4(0.f, 0.f, 0.f, 0.f);
    float den = 0.f;
    for (int j0 = 0; j0 < deg; j0 += 64) {
        int cnt = deg - j0; if (cnt > 64) cnt = 64;
        int msrc = col[base + j0 + lane];
        for (int j4 = 0; j4 < cnt; j4 += 8) {
            int e0 = j4 + grp, e1 = j4 + 4 + grp;
            int s0 = __shfl(msrc, e0, 64);
            int s1 = __shfl(msrc, e1, 64);
            bool v0 = e0 < cnt, v1 = e1 < cnt;
            s0 = v0 ? s0 : 0;
            s1 = v1 ? s1 : 0;
            uint2 ba = *(const uint2*)(xl2b + (size_t)s0 * 64 + 4 * cidx);
            uint2 bb = *(const uint2*)(xl2b + (size_t)s1 * 64 + 4 * cidx);
            float a0 = __uint_as_float(ba.x << 16);
            float a1 = __uint_as_float(ba.x & 0xffff0000u);
            float a2 = __uint_as_float(ba.y << 16);
            float a3 = __uint_as_float(ba.y & 0xffff0000u);
            float b0 = __uint_as_float(bb.x << 16);
            float b1 = __uint_as_float(bb.x & 0xffff0000u);
            float b2 = __uint_as_float(bb.y << 16);
            float b3 = __uint_as_float(bb.y & 0xffff0000u);
            float pa = LEAKY(a0 + xrv.x) * atv.x;
            pa = fmaf(LEAKY(a1 + xrv.y), atv.y, pa);
            pa = fmaf(LEAKY(a2 + xrv.z), atv.z, pa);
            pa = fmaf(LEAKY(a3 + xrv.w), atv.w, pa);
            float pb = LEAKY(b0 + xrv.x) * atv.x;
            pb = fmaf(LEAKY(b1 + xrv.y), atv.y, pb);
            pb = fmaf(LEAKY(b2 + xrv.z), atv.z, pb);
            pb = fmaf(LEAKY(b3 + xrv.w), atv.w, pb);
            pa += __shfl_xor(pa, 1, 64);    // head = 4 lanes
            pa += __shfl_xor(pa, 2, 64);
            pb += __shfl_xor(pb, 1, 64);
            pb += __shfl_xor(pb, 2, 64);
            float ea = v0 ? exp2f(pa) : 0.f;
            float eb = v1 ? exp2f(pb) : 0.f;
            acc.x = fmaf(ea, a0, acc.x); acc.x = fmaf(eb, b0, acc.x);
            acc.y = fmaf(ea, a1, acc.y); acc.y = fmaf(eb, b1, acc.y);
            acc.z = fmaf(ea, a2, acc.z); acc.z = fmaf(eb, b2, acc.z);
            acc.w = fmaf(ea, a3, acc.w); acc.w = fmaf(eb, b3, acc.w);
            den += ea + eb;
        }
    }
    acc.x += __shfl_xor(acc.x, 16, 64); acc.x += __shfl_xor(acc.x, 32, 64);
    acc.y += __shfl_xor(acc.y, 16, 64); acc.y += __shfl_xor(acc.y, 32, 64);
    acc.z += __shfl_xor(acc.z, 16, 64); acc.z += __shfl_xor(acc.z, 32, 64);
    acc.w += __shfl_xor(acc.w, 16, 64); acc.w += __shfl_xor(acc.w, 32, 64);
    den += __shfl_xor(den, 16, 64);
    den += __shfl_xor(den, 32, 64);
    float inv = 1.f / den;
    float4 bi = *(const float4*)(bias + 4 * cidx);
    float4 o;
    o.x = fmaf(acc.x, inv, bi.x);
    o.y = fmaf(acc.y, inv, bi.y);
    o.z = fmaf(acc.z, inv, bi.z);
    o.w = fmaf(acc.w, inv, bi.w);
    if (lane < 16) *(float4*)(C + n * 64 + 4 * cidx) = o;
    // ---- fused BN-stats epilogue ----
    __shared__ float sred[4][64];
    __shared__ float qred[4][64];
    int wv = threadIdx.x >> 6;
    if (lane < 16) {
        int c = 4 * cidx;
        sred[wv][c]     = o.x; qred[wv][c]     = o.x * o.x;
        sred[wv][c + 1] = o.y; qred[wv][c + 1] = o.y * o.y;
        sred[wv][c + 2] = o.z; qred[wv][c + 2] = o.z * o.z;
        sred[wv][c + 3] = o.w; qred[wv][c + 3] = o.w * o.w;
    }
    __syncthreads();
    int t = threadIdx.x;
    if (t < 128) {
        float a;
        if (t < 64) a = sred[0][t] + sred[1][t] + sred[2][t] + sred[3][t];
        else { int c = t - 64; a = qred[0][c] + qred[1][c] + qred[2][c] + qred[3][c]; }
        atomicAdd(&s2r[(blockIdx.x & 63) * 128 + t], a);
    }
}

// ---- replica reduce + BN coefficient finalize (layer 2): single block ----
__global__ void red2_kernel(const float* s2r, const float* g2, const float* be2,
                            float* stats) {
    __shared__ float ls[128];
    int t = threadIdx.x;   // 128 threads
    float a = 0.f;
    for (int r = 0; r < 64; r++) a += s2r[r * 128 + t];
    ls[t] = a;
    __syncthreads();
    if (t < 64) {
        float mu = ls[t] * (1.0f / N_NODES);
        float var = ls[64 + t] * (1.0f / N_NODES) - mu * mu;
        float sc = g2[t] * rsqrtf(var + EPSBN);
        stats[t] = sc;
        stats[64 + t] = be2[t] - mu * sc;
    }
}

// ---- layer 3 linear: wave/node butterfly reduce, fused BN2+ELU ----
__global__ void __launch_bounds__(256) lin3_kernel(
    const float* C, const float* stats2,
    const float* Wl, const float* bl, const float* Wr, const float* br,
    float* xl3, float* xr3)
{
    int gid = blockIdx.x * 256 + threadIdx.x;
    int n = gid >> 6;
    int lane = threadIdx.x & 63;
    if (n >= N_NODES) return;
    float v = fmaf(C[n * 64 + lane], stats2[lane], stats2[64 + lane]);
    float h = v > 0.f ? v : __expf(v) - 1.f;   // ELU
    float2 wlv = *(const float2*)(Wl + 2 * lane);
    float2 wrv = *(const float2*)(Wr + 2 * lane);
    float a0 = h * wlv.x, a1 = h * wlv.y;
    float r0 = h * wrv.x, r1 = h * wrv.y;
    #pragma unroll
    for (int m = 1; m < 64; m <<= 1) {
        a0 += __shfl_xor(a0, m, 64);
        a1 += __shfl_xor(a1, m, 64);
        r0 += __shfl_xor(r0, m, 64);
        r1 += __shfl_xor(r1, m, 64);
    }
    if (lane == 0) {
        xl3[2 * n]     = a0 + bl[0];
        xl3[2 * n + 1] = a1 + bl[1];
        xr3[2 * n]     = r0 + br[0];
        xr3[2 * n + 1] = r1 + br[1];
    }
}

// ---- layer 3 gather: H=1, C=2; 4 lanes/node, fused output ----
__global__ void __launch_bounds__(256) gather3_kernel(
    const int* row_ptr, const int* col,
    const float* xl3, const float* xr3,
    const float* att, const float* bias,
    void* out, const int* flags) {
    int gid = blockIdx.x * 256 + threadIdx.x;
    int n = gid >> 2;                  // 4 lanes per node
    int q = threadIdx.x & 3;
    if (n >= N_NODES) return;
    float a0 = att[0], a1 = att[1];    // pre-scaled by log2e
    float xr0 = xr3[2 * n], xr1 = xr3[2 * n + 1];
    float acc0 = 0.f, acc1 = 0.f, den = 0.f;
    int e0 = row_ptr[n], e1 = row_ptr[n + 1];
    for (int e = e0 + q; e < e1; e += 4) {
        int src = col[e];
        float2 xs = *(const float2*)(xl3 + 2 * src);
        float z0 = LEAKY(xs.x + xr0);
        float z1 = LEAKY(xs.y + xr1);
        float p = exp2f(fmaf(z0, a0, z1 * a1));
        acc0 = fmaf(p, xs.x, acc0);
        acc1 = fmaf(p, xs.y, acc1);
        den += p;
    }
    acc0 += __shfl_xor(acc0, 1, 64); acc0 += __shfl_xor(acc0, 2, 64);
    acc1 += __shfl_xor(acc1, 1, 64); acc1 += __shfl_xor(acc1, 2, 64);
    den  += __shfl_xor(den, 1, 64);  den  += __shfl_xor(den, 2, 64);
    if (q == 0) {
        float inv = 1.f / den;
        float v0 = fmaf(acc0, inv, bias[0]);
        float v1 = fmaf(acc1, inv, bias[1]);
        if (flags[0]) {
            ((float*)out)[2 * n] = v0;
            ((float*)out)[2 * n + 1] = v1;
        } else {
            ((__hip_bfloat16*)out)[2 * n] = __float2bfloat16(v0);
            ((__hip_bfloat16*)out)[2 * n + 1] = __float2bfloat16(v1);
        }
    }
}

extern "C" void kernel_launch(void* const* d_in, const int* in_sizes, int n_in,
                              void* d_out, int out_size, void* d_ws, size_t ws_size,
                              hipStream_t stream) {
    float* W = (float*)d_ws;
    float* C = W + OFF_C;
    float* A = W + OFF_A;
    float* B = W + OFF_B;
    float* STATS = W + OFF_STATS;
    float* S1R = W + OFF_S1R;
    float* S2R = W + OFF_S2R;
    float* P = W + OFF_P;
    int* ROWPTR = (int*)(W + OFF_ROWPTR);
    int* DEG    = (int*)(W + OFF_DEG);
    int* CURSOR = (int*)(W + OFF_CURSOR);
    int* BSUM   = (int*)(W + OFF_BSUM);
    int* COL    = (int*)(W + OFF_COL);
    int* FLAGS  = (int*)(W + OFF_FLAGS);
    int* SCNT   = (int*)(W + OFF_SCNT);
    // bucket segments overlay the C region (C first written by gather1)
    int* DSTB   = (int*)(W + OFF_C);
    int* SRCB   = DSTB + 8 * BK_CAP;

    const int* ei = (const int*)d_in[1];

    float* Px  = P;
    float* W1l = Px + 100000; float* b1l = W1l + 256; float* W1r = b1l + 128; float* b1r = W1r + 256;
    float* a1  = b1r + 128;   float* bias1 = a1 + 128; float* g1 = bias1 + 128; float* be1 = g1 + 128;
    float* W2l = be1 + 128;   float* b2l = W2l + 8192; float* W2r = b2l + 64;  float* b2r = W2r + 8192;
    float* a2  = b2r + 64;    float* bias2 = a2 + 64;  float* g2 = bias2 + 64; float* be2 = g2 + 64;
    float* W3l = be2 + 64;    float* b3l = W3l + 128;  float* W3r = b3l + 2;   float* b3r = W3r + 128;
    float* a3  = b3r + 2;     float* bias3 = a3 + 2;

    prep_kernel<<<196, 256, 0, stream>>>((const unsigned short*)d_in[0], ei, FLAGS, DEG, STATS, S1R, S2R, SCNT);

    ParamPtrs ps;
    ps.p[0] = d_in[0];
    for (int j = 1; j < 23; j++) ps.p[j] = d_in[j + 1];
    convert_kernel<<<(N_PARAM_TOT + 255) / 256, 256, 0, stream>>>(ps, P, FLAGS);

    // ---- CSR build: read-once bucketing (+fused deg count), then scatter ----
    bucket_kernel<<<(N_ET + BK_CHUNK - 1) / BK_CHUNK, 256, 0, stream>>>(ei, FLAGS, SCNT, DSTB, SRCB, DEG);
    scan1_kernel<<<196, 256, 0, stream>>>(DEG, ROWPTR, BSUM);
    scan23_kernel<<<196, 256, 0, stream>>>(ROWPTR, CURSOR, BSUM);
    scatter2_kernel<<<256, 256, 0, stream>>>(SCNT, DSTB, SRCB, CURSOR, COL);

    // ---- layer 1 (BN stats fused into gather epilogue; bf16 C table) ----
    gather1_kernel<<<N_NODES * 64 / 256, 256, 0, stream>>>(ROWPTR, COL, Px, W1l, b1l, W1r, b1r, a1, bias1, (unsigned int*)C, S1R);
    red1_kernel<<<1, 256, 0, stream>>>(S1R, g1, be1, STATS);

    // ---- layer 2 (BN1+ELU via precomputed coeffs; bf16 xl2 table; stats fused) ----
    lin2_kernel<<<(N_NODES + 63) / 64, 256, 0, stream>>>((const unsigned int*)C, STATS, W2l, b2l, W2r, b2r, (unsigned short*)A, B);
    gather2_kernel<<<N_NODES * 64 / 256, 256, 0, stream>>>(ROWPTR, COL, (const unsigned short*)A, B, a2, bias2, C, S2R);
    red2_kernel<<<1, 128, 0, stream>>>(S2R, g2, be2, STATS + 256);

    // ---- layer 3 (BN2+ELU via precomputed coeffs fused into lin3) ----
    lin3_kernel<<<N_NODES * 64 / 256, 256, 0, stream>>>(C, STATS + 256, W3l, b3l, W3r, b3r, A, B);
    gather3_kernel<<<(N_NODES * 4 + 255) / 256, 256, 0, stream>>>(ROWPTR, COL, A, B, a3, bias3, d_out, FLAGS);
}

// Round 16
// 333.062 us; speedup vs baseline: 1.0215x; 1.0083x over previous
//
#include <hip/hip_runtime.h>
#include <hip/hip_bf16.h>

#define N_NODES 50000
#define N_E0    800000
#define N_ET    850000
#define EPSBN   1e-5f
#define LOG2E   1.4426950408889634f

#define LEAKY(z) fmaxf((z), 0.2f * (z))

// ---- workspace layout (32-bit word offsets) ----
#define OFF_C 0                 // layer1 C bf16-packed (64N words); overlaid by DSTB/SRCB during CSR build; layer2 C f32
#define OFF_A (128*N_NODES)     // xl2b (bf16) / xl3
#define OFF_B (192*N_NODES)     // xr2 (f32) / xr3
#define OFF_STATS (256*N_NODES)
#define OFF_S1R (OFF_STATS + 512)            // 64 replicas x 256
#define OFF_S2R (OFF_S1R + 16384)            // 64 replicas x 128
#define OFF_P (OFF_S2R + 8192)
#define N_PARAM_TOT 118312
#define OFF_ROWPTR (OFF_P + N_PARAM_TOT)      // 50001 ints
#define OFF_DEG    (OFF_ROWPTR + 50001)       // 50000 ints
#define OFF_CURSOR (OFF_DEG + 50000)          // 50000 ints
#define OFF_BSUM   (OFF_CURSOR + 50000)       // 256 ints
#define OFF_COL    (OFF_BSUM + 256)           // 850000 + 64 pad ints
#define OFF_FLAGS  (OFF_COL + 850064)         // 2 ints
#define OFF_SCNT   (OFF_FLAGS + 2)            // 8 stripe cursors

// per-stripe bucket segments, overlaid on the C region (C written later)
#define BK_CAP 131072
#define BK_CHUNK 2048

__device__ __forceinline__ float bf2f(unsigned short u) {
    return __uint_as_float(((unsigned int)u) << 16);
}
__device__ __forceinline__ unsigned short f2bf(float f) {
    unsigned int u = __float_as_uint(f);
    u += 0x7FFFu + ((u >> 16) & 1u);    // round-to-nearest-even
    return (unsigned short)(u >> 16);
}

// ---- prep: dtype detect (block 0) + deg/stats/replica/scnt init ----
__global__ void prep_kernel(const unsigned short* xr, const int* ei, int* flags,
                            int* deg, float* stats, float* s1r, float* s2r, int* scnt) {
    int i = blockIdx.x * 256 + threadIdx.x;
    if (i < N_NODES) deg[i] = 0;   // counted in bucket_kernel
    if (i < 512) stats[i] = 0.f;
    if (i < 16384) s1r[i] = 0.f;
    if (i < 8192)  s2r[i] = 0.f;
    if (i < 8) scnt[i] = 0;
    if (blockIdx.x == 0) {
        __shared__ int c1, c2;
        if (threadIdx.x == 0) { c1 = 0; c2 = 0; }
        __syncthreads();
        int t = threadIdx.x;
        int l1 = 0, l2 = 0;
        for (int k = t; k < 2048; k += 256) {
            float v = bf2f(xr[k]);
            if (!(fabsf(v) <= 100.0f)) l1++;
            if (ei[2 * k + 1] != 0) l2++;
        }
        atomicAdd(&c1, l1);
        atomicAdd(&c2, l2);
        __syncthreads();
        if (t == 0) {
            flags[0] = (c1 > 16) ? 1 : 0;   // 1 => inputs are f32
            flags[1] = (c2 == 0) ? 1 : 0;   // 1 => edge_index is int64
        }
    }
}

struct ParamPtrs { const void* p[23]; };

// stage f32 params; att vectors (t=5,13,21) pre-scaled by log2e so softmax uses exp2
__global__ void convert_kernel(ParamPtrs ps, float* dst, const int* flags) {
    const int sizes[23] = {100000, 256,128,256,128,128,128,128,128,
                           8192,64,8192,64,64,64,64,64,
                           128,2,128,2,2,2};
    int g = blockIdx.x * 256 + threadIdx.x;
    if (g >= N_PARAM_TOT) return;
    int t = 0, off = g;
    while (off >= sizes[t]) { off -= sizes[t]; t++; }
    float v;
    if (flags[0]) v = ((const float*)ps.p[t])[off];
    else          v = bf2f(((const unsigned short*)ps.p[t])[off]);
    if (t == 5 || t == 13 || t == 21) v *= LOG2E;
    dst[g] = v;
}

// ---- pass 1: read edges ONCE; bucket (dst,src) into 8 stripes AND count deg ----
__global__ void bucket_kernel(const int* ei, const int* flags, int* scnt,
                              int* dstb, int* srcb, int* deg) {
    __shared__ int lcnt[8];
    __shared__ int lbase[8];
    int tid = threadIdx.x;
    if (tid < 8) lcnt[tid] = 0;
    __syncthreads();
    int base_e = blockIdx.x * BK_CHUNK;
    int i64 = flags[1];
    int src[8], dst[8], pos[8];
    #pragma unroll
    for (int u = 0; u < 8; u++) {
        int e = base_e + u * 256 + tid;
        if (e < N_ET) {
            int s, d;
            if (e < N_E0) {
                d = i64 ? ei[2 * (N_E0 + e)] : ei[N_E0 + e];
                s = i64 ? ei[2 * e] : ei[e];
            } else { s = d = e - N_E0; }
            src[u] = s; dst[u] = d;
            pos[u] = atomicAdd(&lcnt[d / 6250], 1);
            atomicAdd(&deg[d], 1);           // fused histogram
        } else dst[u] = -1;
    }
    __syncthreads();
    if (tid < 8) lbase[tid] = atomicAdd(&scnt[tid], lcnt[tid]);
    __syncthreads();
    #pragma unroll
    for (int u = 0; u < 8; u++) {
        if (dst[u] >= 0) {
            int st = dst[u] / 6250;
            int gp = st * BK_CAP + lbase[st] + pos[u];
            dstb[gp] = dst[u];
            srcb[gp] = src[u];
        }
    }
}

__global__ void scan1_kernel(const int* deg, int* row_ptr, int* bsum) {
    __shared__ int sh[256];
    int i = blockIdx.x * 256 + threadIdx.x;
    int v = (i < N_NODES) ? deg[i] : 0;
    sh[threadIdx.x] = v;
    __syncthreads();
    for (int off = 1; off < 256; off <<= 1) {
        int t = (threadIdx.x >= off) ? sh[threadIdx.x - off] : 0;
        __syncthreads();
        sh[threadIdx.x] += t;
        __syncthreads();
    }
    if (i < N_NODES) row_ptr[i] = sh[threadIdx.x] - v;
    if (threadIdx.x == 255) bsum[blockIdx.x] = sh[255];
}

__global__ void scan23_kernel(int* row_ptr, int* cursor, const int* bsum) {
    __shared__ int sh[256];
    int t = threadIdx.x;
    int v = (t < 196) ? bsum[t] : 0;
    sh[t] = v;
    __syncthreads();
    for (int off = 1; off < 256; off <<= 1) {
        int u = (t >= off) ? sh[t - off] : 0;
        __syncthreads();
        sh[t] += u;
        __syncthreads();
    }
    int prefix = (blockIdx.x == 0) ? 0 : sh[blockIdx.x - 1];
    int i = blockIdx.x * 256 + t;
    if (i < N_NODES) {
        int r = row_ptr[i] + prefix;
        row_ptr[i] = r;
        cursor[i] = r;
    }
    if (i == 0) row_ptr[N_NODES] = N_ET;
}

// ---- pass 2: striped scatter, reads own segment once; col writes XCD-local ----
__global__ void scatter2_kernel(const int* scnt, const int* dstb, const int* srcb,
                                int* cursor, int* col) {
    int stripe = blockIdx.x & 7;
    int bi = blockIdx.x >> 3;
    int cnt = scnt[stripe];
    int off = stripe * BK_CAP;
    for (int t = bi * 256 + threadIdx.x; t < cnt; t += 32 * 256) {
        int d = dstb[off + t];
        int pos = atomicAdd(&cursor[d], 1);
        col[pos] = srcb[off + t];
    }
}

// ---- layer 1 gather (measured-best form): wave/node, 2ch/lane, unroll-8,
// readlane scalar-broadcast path. bf16-packed C out.
__global__ void __launch_bounds__(256) gather1_kernel(
    const int* row_ptr, const int* col, const float* x,
    const float* W1l, const float* b1l, const float* W1r, const float* b1r,
    const float* att, const float* bias, unsigned int* Cb, float* s1r)
{
    int gid = blockIdx.x * 256 + threadIdx.x;
    int n = gid >> 6;
    int lane = threadIdx.x & 63;
    float2 wl0 = *(const float2*)(W1l + 2 * lane);
    float2 wl1 = *(const float2*)(W1l + 128 + 2 * lane);
    float2 bl  = *(const float2*)(b1l + 2 * lane);
    float2 wr0 = *(const float2*)(W1r + 2 * lane);
    float2 wr1 = *(const float2*)(W1r + 128 + 2 * lane);
    float2 br  = *(const float2*)(b1r + 2 * lane);
    float2 at  = *(const float2*)(att + 2 * lane);   // pre-scaled by log2e
    float2 xd  = *(const float2*)(x + 2 * n);
    float xr0 = fmaf(xd.x, wr0.x, fmaf(xd.y, wr1.x, br.x));
    float xr1 = fmaf(xd.x, wr0.y, fmaf(xd.y, wr1.y, br.y));
    int base = __builtin_amdgcn_readfirstlane(row_ptr[n]);
    int deg  = __builtin_amdgcn_readfirstlane(row_ptr[n + 1]) - base;
    float acc0 = 0.f, acc1 = 0.f, den = 0.f;
    for (int j0 = 0; j0 < deg; j0 += 64) {
        int cnt = deg - j0; if (cnt > 64) cnt = 64;
        int msrc = col[base + j0 + lane];   // COL padded by 64: unmasked OK
        int j = 0;
        for (; j + 8 <= cnt; j += 8) {
            int s[8];
            #pragma unroll
            for (int u = 0; u < 8; u++) s[u] = __builtin_amdgcn_readlane(msrc, j + u);
            float2 xs[8];
            #pragma unroll
            for (int u = 0; u < 8; u++) xs[u] = *(const float2*)(x + 2 * s[u]);
            float xl0[8], xl1[8], part[8];
            #pragma unroll
            for (int u = 0; u < 8; u++) {
                xl0[u] = fmaf(xs[u].x, wl0.x, fmaf(xs[u].y, wl1.x, bl.x));
                xl1[u] = fmaf(xs[u].x, wl0.y, fmaf(xs[u].y, wl1.y, bl.y));
                float z0 = LEAKY(xl0[u] + xr0);
                float z1 = LEAKY(xl1[u] + xr1);
                part[u] = fmaf(z0, at.x, z1 * at.y);
            }
            #pragma unroll
            for (int m = 1; m <= 4; m <<= 1) {
                #pragma unroll
                for (int u = 0; u < 8; u++) part[u] += __shfl_xor(part[u], m, 64);
            }
            #pragma unroll
            for (int u = 0; u < 8; u++) {
                float p = exp2f(part[u]);
                acc0 = fmaf(p, xl0[u], acc0);
                acc1 = fmaf(p, xl1[u], acc1);
                den += p;
            }
        }
        for (; j < cnt; ++j) {
            int s0 = __builtin_amdgcn_readlane(msrc, j);
            float2 xs = *(const float2*)(x + 2 * s0);
            float xl0s = fmaf(xs.x, wl0.x, fmaf(xs.y, wl1.x, bl.x));
            float xl1s = fmaf(xs.x, wl0.y, fmaf(xs.y, wl1.y, bl.y));
            float z0 = LEAKY(xl0s + xr0);
            float z1 = LEAKY(xl1s + xr1);
            float part = fmaf(z0, at.x, z1 * at.y);
            part += __shfl_xor(part, 1, 64);
            part += __shfl_xor(part, 2, 64);
            part += __shfl_xor(part, 4, 64);
            float p = exp2f(part);
            acc0 = fmaf(p, xl0s, acc0);
            acc1 = fmaf(p, xl1s, acc1);
            den += p;
        }
    }
    float inv = 1.f / den;
    float2 bi = *(const float2*)(bias + 2 * lane);
    float2 outv;
    outv.x = fmaf(acc0, inv, bi.x);
    outv.y = fmaf(acc1, inv, bi.y);
    Cb[n * 64 + lane] = ((unsigned int)f2bf(outv.y) << 16) | f2bf(outv.x);
    // ---- fused BN-stats epilogue (4 nodes per block) ----
    __shared__ float sred[4][128];
    __shared__ float qred[4][128];
    int wv = threadIdx.x >> 6;
    sred[wv][2 * lane]     = outv.x;
    sred[wv][2 * lane + 1] = outv.y;
    qred[wv][2 * lane]     = outv.x * outv.x;
    qred[wv][2 * lane + 1] = outv.y * outv.y;
    __syncthreads();
    int t = threadIdx.x;
    float a;
    if (t < 128) a = sred[0][t] + sred[1][t] + sred[2][t] + sred[3][t];
    else { int c = t - 128; a = qred[0][c] + qred[1][c] + qred[2][c] + qred[3][c]; }
    atomicAdd(&s1r[(blockIdx.x & 63) * 256 + t], a);
}

// ---- replica reduce + BN coefficient finalize (layer 1): single block.
// Writes stats[k]=scale, stats[128+k]=offset so lin2 staging is 1 fma.
__global__ void red1_kernel(const float* s1r, const float* g1, const float* be1,
                            float* stats) {
    __shared__ float ls[256];
    int t = threadIdx.x;
    float a = 0.f;
    for (int r = 0; r < 64; r++) a += s1r[r * 256 + t];
    ls[t] = a;
    __syncthreads();
    if (t < 128) {
        float mu = ls[t] * (1.0f / N_NODES);
        float var = ls[128 + t] * (1.0f / N_NODES) - mu * mu;
        float sc = g1[t] * rsqrtf(var + EPSBN);
        stats[t] = sc;
        stats[128 + t] = be1[t] - mu * sc;
    }
}

// ---- layer 2 linear, register-tiled, fused BN1+ELU on staging (bf16 C in).
// xl2 written as bf16 (gather2's random-gather table); xr2 stays f32.
__global__ void __launch_bounds__(256) lin2_kernel(
    const unsigned int* Cb, const float* stats, const float* Wl, const float* bl,
    const float* Wr, const float* br, unsigned short* xl2b, float* xr2)
{
    __shared__ float h[64 * 132];
    int tid = threadIdx.x;
    int nb = blockIdx.x * 64;
    for (int i = tid; i < 64 * 64; i += 256) {      // uint = 2 bf16 channels
        int ni = i >> 6, kp = i & 63;
        int n = nb + ni;
        int k = 2 * kp;
        float v0 = 0.f, v1 = 0.f;
        if (n < N_NODES) {
            unsigned int pk = Cb[n * 64 + kp];
            float b0 = fmaf(__uint_as_float(pk << 16),        stats[k],     stats[128 + k]);
            float b1 = fmaf(__uint_as_float(pk & 0xffff0000u), stats[k + 1], stats[128 + k + 1]);
            v0 = b0 > 0.f ? b0 : __expf(b0) - 1.f;   // ELU
            v1 = b1 > 0.f ? b1 : __expf(b1) - 1.f;
        }
        h[ni * 132 + k]     = v0;
        h[ni * 132 + k + 1] = v1;
    }
    __syncthreads();
    int kt = (tid & 15) * 4;
    int nt = (tid >> 4) * 4;
    float accl[4][4], accr[4][4];
    #pragma unroll
    for (int i = 0; i < 4; i++) {
        #pragma unroll
        for (int k = 0; k < 4; k++) { accl[i][k] = 0.f; accr[i][k] = 0.f; }
    }
    for (int j = 0; j < 128; j += 4) {
        float4 hv[4];
        #pragma unroll
        for (int i = 0; i < 4; i++)
            hv[i] = *(const float4*)&h[(nt + i) * 132 + j];
        #pragma unroll
        for (int jj = 0; jj < 4; jj++) {
            float4 wl4 = *(const float4*)&Wl[(j + jj) * 64 + kt];
            float4 wr4 = *(const float4*)&Wr[(j + jj) * 64 + kt];
            #pragma unroll
            for (int i = 0; i < 4; i++) {
                float hvv = (jj == 0) ? hv[i].x : (jj == 1) ? hv[i].y :
                            (jj == 2) ? hv[i].z : hv[i].w;
                accl[i][0] += hvv * wl4.x; accl[i][1] += hvv * wl4.y;
                accl[i][2] += hvv * wl4.z; accl[i][3] += hvv * wl4.w;
                accr[i][0] += hvv * wr4.x; accr[i][1] += hvv * wr4.y;
                accr[i][2] += hvv * wr4.z; accr[i][3] += hvv * wr4.w;
            }
        }
    }
    float4 blv = *(const float4*)&bl[kt];
    float4 brv = *(const float4*)&br[kt];
    #pragma unroll
    for (int i = 0; i < 4; i++) {
        int n = nb + nt + i;
        if (n < N_NODES) {
            ushort4 ob;
            ob.x = f2bf(accl[i][0] + blv.x);
            ob.y = f2bf(accl[i][1] + blv.y);
            ob.z = f2bf(accl[i][2] + blv.z);
            ob.w = f2bf(accl[i][3] + blv.w);
            *(ushort4*)&xl2b[n * 64 + kt] = ob;
            float4 o;
            o.x = accr[i][0] + brv.x; o.y = accr[i][1] + brv.y;
            o.z = accr[i][2] + brv.z; o.w = accr[i][3] + brv.w;
            *(float4*)&xr2[n * 64 + kt] = o;
        }
    }
}

// ---- layer 2 gather: 4 edges/wave, 16 lanes/edge, 4 bf16 ch/lane ----
__global__ void __launch_bounds__(256) gather2_kernel(
    const int* row_ptr, const int* col, const unsigned short* xl2b, const float* xr2,
    const float* att, const float* bias, float* C, float* s2r)
{
    int gid = blockIdx.x * 256 + threadIdx.x;
    int n = gid >> 6;
    int lane = threadIdx.x & 63;
    int grp = lane >> 4;       // edge slot (0..3)
    int cidx = lane & 15;      // ch = 4*cidx .. +3
    float4 xrv = *(const float4*)(xr2 + n * 64 + 4 * cidx);
    float4 atv = *(const float4*)(att + 4 * cidx);   // pre-scaled by log2e
    int base = __builtin_amdgcn_readfirstlane(row_ptr[n]);
    int deg  = __builtin_amdgcn_readfirstlane(row_ptr[n + 1]) - base;
    float4 acc = make_float4(0.f, 0.f, 0.f, 0.f);
    float den = 0.f;
    for (int j0 = 0; j0 < deg; j0 += 64) {
        int cnt = deg - j0; if (cnt > 64) cnt = 64;
        int msrc = col[base + j0 + lane];
        for (int j4 = 0; j4 < cnt; j4 += 8) {
            int e0 = j4 + grp, e1 = j4 + 4 + grp;
            int s0 = __shfl(msrc, e0, 64);
            int s1 = __shfl(msrc, e1, 64);
            bool v0 = e0 < cnt, v1 = e1 < cnt;
            s0 = v0 ? s0 : 0;
            s1 = v1 ? s1 : 0;
            uint2 ba = *(const uint2*)(xl2b + (size_t)s0 * 64 + 4 * cidx);
            uint2 bb = *(const uint2*)(xl2b + (size_t)s1 * 64 + 4 * cidx);
            float a0 = __uint_as_float(ba.x << 16);
            float a1 = __uint_as_float(ba.x & 0xffff0000u);
            float a2 = __uint_as_float(ba.y << 16);
            float a3 = __uint_as_float(ba.y & 0xffff0000u);
            float b0 = __uint_as_float(bb.x << 16);
            float b1 = __uint_as_float(bb.x & 0xffff0000u);
            float b2 = __uint_as_float(bb.y << 16);
            float b3 = __uint_as_float(bb.y & 0xffff0000u);
            float pa = LEAKY(a0 + xrv.x) * atv.x;
            pa = fmaf(LEAKY(a1 + xrv.y), atv.y, pa);
            pa = fmaf(LEAKY(a2 + xrv.z), atv.z, pa);
            pa = fmaf(LEAKY(a3 + xrv.w), atv.w, pa);
            float pb = LEAKY(b0 + xrv.x) * atv.x;
            pb = fmaf(LEAKY(b1 + xrv.y), atv.y, pb);
            pb = fmaf(LEAKY(b2 + xrv.z), atv.z, pb);
            pb = fmaf(LEAKY(b3 + xrv.w), atv.w, pb);
            pa += __shfl_xor(pa, 1, 64);    // head = 4 lanes
            pa += __shfl_xor(pa, 2, 64);
            pb += __shfl_xor(pb, 1, 64);
            pb += __shfl_xor(pb, 2, 64);
            float ea = v0 ? exp2f(pa) : 0.f;
            float eb = v1 ? exp2f(pb) : 0.f;
            acc.x = fmaf(ea, a0, acc.x); acc.x = fmaf(eb, b0, acc.x);
            acc.y = fmaf(ea, a1, acc.y); acc.y = fmaf(eb, b1, acc.y);
            acc.z = fmaf(ea, a2, acc.z); acc.z = fmaf(eb, b2, acc.z);
            acc.w = fmaf(ea, a3, acc.w); acc.w = fmaf(eb, b3, acc.w);
            den += ea + eb;
        }
    }
    acc.x += __shfl_xor(acc.x, 16, 64); acc.x += __shfl_xor(acc.x, 32, 64);
    acc.y += __shfl_xor(acc.y, 16, 64); acc.y += __shfl_xor(acc.y, 32, 64);
    acc.z += __shfl_xor(acc.z, 16, 64); acc.z += __shfl_xor(acc.z, 32, 64);
    acc.w += __shfl_xor(acc.w, 16, 64); acc.w += __shfl_xor(acc.w, 32, 64);
    den += __shfl_xor(den, 16, 64);
    den += __shfl_xor(den, 32, 64);
    float inv = 1.f / den;
    float4 bi = *(const float4*)(bias + 4 * cidx);
    float4 o;
    o.x = fmaf(acc.x, inv, bi.x);
    o.y = fmaf(acc.y, inv, bi.y);
    o.z = fmaf(acc.z, inv, bi.z);
    o.w = fmaf(acc.w, inv, bi.w);
    if (lane < 16) *(float4*)(C + n * 64 + 4 * cidx) = o;
    // ---- fused BN-stats epilogue ----
    __shared__ float sred[4][64];
    __shared__ float qred[4][64];
    int wv = threadIdx.x >> 6;
    if (lane < 16) {
        int c = 4 * cidx;
        sred[wv][c]     = o.x; qred[wv][c]     = o.x * o.x;
        sred[wv][c + 1] = o.y; qred[wv][c + 1] = o.y * o.y;
        sred[wv][c + 2] = o.z; qred[wv][c + 2] = o.z * o.z;
        sred[wv][c + 3] = o.w; qred[wv][c + 3] = o.w * o.w;
    }
    __syncthreads();
    int t = threadIdx.x;
    if (t < 128) {
        float a;
        if (t < 64) a = sred[0][t] + sred[1][t] + sred[2][t] + sred[3][t];
        else { int c = t - 64; a = qred[0][c] + qred[1][c] + qred[2][c] + qred[3][c]; }
        atomicAdd(&s2r[(blockIdx.x & 63) * 128 + t], a);
    }
}

// ---- replica reduce + BN coefficient finalize (layer 2): single block ----
__global__ void red2_kernel(const float* s2r, const float* g2, const float* be2,
                            float* stats) {
    __shared__ float ls[128];
    int t = threadIdx.x;   // 128 threads
    float a = 0.f;
    for (int r = 0; r < 64; r++) a += s2r[r * 128 + t];
    ls[t] = a;
    __syncthreads();
    if (t < 64) {
        float mu = ls[t] * (1.0f / N_NODES);
        float var = ls[64 + t] * (1.0f / N_NODES) - mu * mu;
        float sc = g2[t] * rsqrtf(var + EPSBN);
        stats[t] = sc;
        stats[64 + t] = be2[t] - mu * sc;
    }
}

// ---- layer 3 linear: wave/node butterfly reduce, fused BN2+ELU ----
__global__ void __launch_bounds__(256) lin3_kernel(
    const float* C, const float* stats2,
    const float* Wl, const float* bl, const float* Wr, const float* br,
    float* xl3, float* xr3)
{
    int gid = blockIdx.x * 256 + threadIdx.x;
    int n = gid >> 6;
    int lane = threadIdx.x & 63;
    if (n >= N_NODES) return;
    float v = fmaf(C[n * 64 + lane], stats2[lane], stats2[64 + lane]);
    float h = v > 0.f ? v : __expf(v) - 1.f;   // ELU
    float2 wlv = *(const float2*)(Wl + 2 * lane);
    float2 wrv = *(const float2*)(Wr + 2 * lane);
    float a0 = h * wlv.x, a1 = h * wlv.y;
    float r0 = h * wrv.x, r1 = h * wrv.y;
    #pragma unroll
    for (int m = 1; m < 64; m <<= 1) {
        a0 += __shfl_xor(a0, m, 64);
        a1 += __shfl_xor(a1, m, 64);
        r0 += __shfl_xor(r0, m, 64);
        r1 += __shfl_xor(r1, m, 64);
    }
    if (lane == 0) {
        xl3[2 * n]     = a0 + bl[0];
        xl3[2 * n + 1] = a1 + bl[1];
        xr3[2 * n]     = r0 + br[0];
        xr3[2 * n + 1] = r1 + br[1];
    }
}

// ---- layer 3 gather: H=1, C=2; 4 lanes/node, fused output ----
__global__ void __launch_bounds__(256) gather3_kernel(
    const int* row_ptr, const int* col,
    const float* xl3, const float* xr3,
    const float* att, const float* bias,
    void* out, const int* flags) {
    int gid = blockIdx.x * 256 + threadIdx.x;
    int n = gid >> 2;                  // 4 lanes per node
    int q = threadIdx.x & 3;
    if (n >= N_NODES) return;
    float a0 = att[0], a1 = att[1];    // pre-scaled by log2e
    float xr0 = xr3[2 * n], xr1 = xr3[2 * n + 1];
    float acc0 = 0.f, acc1 = 0.f, den = 0.f;
    int e0 = row_ptr[n], e1 = row_ptr[n + 1];
    for (int e = e0 + q; e < e1; e += 4) {
        int src = col[e];
        float2 xs = *(const float2*)(xl3 + 2 * src);
        float z0 = LEAKY(xs.x + xr0);
        float z1 = LEAKY(xs.y + xr1);
        float p = exp2f(fmaf(z0, a0, z1 * a1));
        acc0 = fmaf(p, xs.x, acc0);
        acc1 = fmaf(p, xs.y, acc1);
        den += p;
    }
    acc0 += __shfl_xor(acc0, 1, 64); acc0 += __shfl_xor(acc0, 2, 64);
    acc1 += __shfl_xor(acc1, 1, 64); acc1 += __shfl_xor(acc1, 2, 64);
    den  += __shfl_xor(den, 1, 64);  den  += __shfl_xor(den, 2, 64);
    if (q == 0) {
        float inv = 1.f / den;
        float v0 = fmaf(acc0, inv, bias[0]);
        float v1 = fmaf(acc1, inv, bias[1]);
        if (flags[0]) {
            ((float*)out)[2 * n] = v0;
            ((float*)out)[2 * n + 1] = v1;
        } else {
            ((__hip_bfloat16*)out)[2 * n] = __float2bfloat16(v0);
            ((__hip_bfloat16*)out)[2 * n + 1] = __float2bfloat16(v1);
        }
    }
}

extern "C" void kernel_launch(void* const* d_in, const int* in_sizes, int n_in,
                              void* d_out, int out_size, void* d_ws, size_t ws_size,
                              hipStream_t stream) {
    float* W = (float*)d_ws;
    float* C = W + OFF_C;
    float* A = W + OFF_A;
    float* B = W + OFF_B;
    float* STATS = W + OFF_STATS;
    float* S1R = W + OFF_S1R;
    float* S2R = W + OFF_S2R;
    float* P = W + OFF_P;
    int* ROWPTR = (int*)(W + OFF_ROWPTR);
    int* DEG    = (int*)(W + OFF_DEG);
    int* CURSOR = (int*)(W + OFF_CURSOR);
    int* BSUM   = (int*)(W + OFF_BSUM);
    int* COL    = (int*)(W + OFF_COL);
    int* FLAGS  = (int*)(W + OFF_FLAGS);
    int* SCNT   = (int*)(W + OFF_SCNT);
    // bucket segments overlay the C region (C first written by gather1)
    int* DSTB   = (int*)(W + OFF_C);
    int* SRCB   = DSTB + 8 * BK_CAP;

    const int* ei = (const int*)d_in[1];

    float* Px  = P;
    float* W1l = Px + 100000; float* b1l = W1l + 256; float* W1r = b1l + 128; float* b1r = W1r + 256;
    float* a1  = b1r + 128;   float* bias1 = a1 + 128; float* g1 = bias1 + 128; float* be1 = g1 + 128;
    float* W2l = be1 + 128;   float* b2l = W2l + 8192; float* W2r = b2l + 64;  float* b2r = W2r + 8192;
    float* a2  = b2r + 64;    float* bias2 = a2 + 64;  float* g2 = bias2 + 64; float* be2 = g2 + 64;
    float* W3l = be2 + 64;    float* b3l = W3l + 128;  float* W3r = b3l + 2;   float* b3r = W3r + 128;
    float* a3  = b3r + 2;     float* bias3 = a3 + 2;

    prep_kernel<<<196, 256, 0, stream>>>((const unsigned short*)d_in[0], ei, FLAGS, DEG, STATS, S1R, S2R, SCNT);

    ParamPtrs ps;
    ps.p[0] = d_in[0];
    for (int j = 1; j < 23; j++) ps.p[j] = d_in[j + 1];
    convert_kernel<<<(N_PARAM_TOT + 255) / 256, 256, 0, stream>>>(ps, P, FLAGS);

    // ---- CSR build: read-once bucketing (+fused deg count), then scatter ----
    bucket_kernel<<<(N_ET + BK_CHUNK - 1) / BK_CHUNK, 256, 0, stream>>>(ei, FLAGS, SCNT, DSTB, SRCB, DEG);
    scan1_kernel<<<196, 256, 0, stream>>>(DEG, ROWPTR, BSUM);
    scan23_kernel<<<196, 256, 0, stream>>>(ROWPTR, CURSOR, BSUM);
    scatter2_kernel<<<256, 256, 0, stream>>>(SCNT, DSTB, SRCB, CURSOR, COL);

    // ---- layer 1 (BN stats fused into gather epilogue; bf16 C table) ----
    gather1_kernel<<<N_NODES * 64 / 256, 256, 0, stream>>>(ROWPTR, COL, Px, W1l, b1l, W1r, b1r, a1, bias1, (unsigned int*)C, S1R);
    red1_kernel<<<1, 256, 0, stream>>>(S1R, g1, be1, STATS);

    // ---- layer 2 (BN1+ELU via precomputed coeffs; bf16 xl2 table; stats fused) ----
    lin2_kernel<<<(N_NODES + 63) / 64, 256, 0, stream>>>((const unsigned int*)C, STATS, W2l, b2l, W2r, b2r, (unsigned short*)A, B);
    gather2_kernel<<<N_NODES * 64 / 256, 256, 0, stream>>>(ROWPTR, COL, (const unsigned short*)A, B, a2, bias2, C, S2R);
    red2_kernel<<<1, 128, 0, stream>>>(S2R, g2, be2, STATS + 256);

    // ---- layer 3 (BN2+ELU via precomputed coeffs fused into lin3) ----
    lin3_kernel<<<N_NODES * 64 / 256, 256, 0, stream>>>(C, STATS + 256, W3l, b3l, W3r, b3r, A, B);
    gather3_kernel<<<(N_NODES * 4 + 255) / 256, 256, 0, stream>>>(ROWPTR, COL, A, B, a3, bias3, d_out, FLAGS);
}